// Round 2
// baseline (674.206 us; speedup 1.0000x reference)
//
#include <hip/hip_runtime.h>
#include <math.h>

#define BB 4
#define NN 8192
#define TOTAL (BB*NN)        // 32768 points
#define KNBR 9
#define CH 7
#define NCHUNK 2
#define CHUNK (NN/NCHUNK)    // 4096
#define BN_EPS 1e-5f
#define M_ELEMS (TOTAL*KNBR) // 294912

// workspace layout (bytes); lifetimes:
//   pts: pack->geom     pd/pi: knn->geom     h1: geom->mm2
//   h2: mm2->final (reuses pts+pd+pi region)  stats: geom->final
#define OFF_PTS   0                       // 524288 B
#define OFF_PD    524288                  // 32768*20*4 = 2621440
#define OFF_PI    3145728                 // 2621440
#define OFF_H2    0                       // 8257536 (overlaps pts/pd/pi, dead by mm2)
#define OFF_STATS 8388608                 // 112 B
#define OFF_H1    8388736                 // 8257536, ends 16646272

// ---------------------------------------------------------------- pack x -> (x,y,z,|x|^2)
__global__ __launch_bounds__(256) void pack_k(const float* __restrict__ x, float4* __restrict__ pts) {
    int i = blockIdx.x * 256 + threadIdx.x;
    if (i >= TOTAL) return;
    float a = x[3*i], b = x[3*i+1], c = x[3*i+2];
    // match reference rounding: (a*a + b*b) + c*c, no fma contraction
    float sq = __fadd_rn(__fadd_rn(__fmul_rn(a,a), __fmul_rn(b,b)), __fmul_rn(c,c));
    pts[i] = make_float4(a, b, c, sq);
}

// sorted top-10 insert (desc by d; strict > => lower index wins ties, matches lax.top_k)
__device__ __forceinline__ void insert10(float (&dl)[10], int (&il)[10], float d, int ii) {
    if (d > dl[9]) {
        bool c0 = d > dl[0];
#pragma unroll
        for (int p = 9; p > 0; p--) {
            bool here = d > dl[p];
            bool up   = d > dl[p-1];
            float nd = up ? dl[p-1] : d;
            int   ni = up ? il[p-1] : ii;
            if (here) { dl[p] = nd; il[p] = ni; }
        }
        if (c0) { dl[0] = d; il[0] = ii; }
    }
}

// ---------------------------------------------------------------- KNN partial top-10 per candidate chunk
// Candidates are wave-uniform -> scalar (SGPR) broadcast loads; no LDS.
__global__ __launch_bounds__(256) void knn_k(const float4* __restrict__ pts,
                                             float* __restrict__ pd, int* __restrict__ pi) {
    int b = blockIdx.z, chunk = blockIdx.y;
    int q = blockIdx.x * 256 + threadIdx.x;      // query index within batch
    const float4* __restrict__ base = pts + b * NN;
    float4 qp = base[q];
    float qn = -qp.w;                            // -xsq_n

    float dl[10]; int il[10];
#pragma unroll
    for (int j = 0; j < 10; j++) { dl[j] = -INFINITY; il[j] = 0; }

    const float4* __restrict__ cand = base + chunk * CHUNK;
    const int c0 = chunk * CHUNK;

    for (int t = 0; t < CHUNK; t += 4) {
        // uniform-address loads -> s_load; precompute 4 distances (ILP), then guarded inserts
        float4 ca = cand[t+0];
        float4 cb = cand[t+1];
        float4 cc = cand[t+2];
        float4 cd = cand[t+3];
        float d0, d1, d2, d3;
        {
            float dot = __fadd_rn(__fadd_rn(__fmul_rn(qp.x,ca.x), __fmul_rn(qp.y,ca.y)), __fmul_rn(qp.z,ca.z));
            d0 = __fsub_rn(__fadd_rn(__fmul_rn(2.0f,dot), qn), ca.w);
        }
        {
            float dot = __fadd_rn(__fadd_rn(__fmul_rn(qp.x,cb.x), __fmul_rn(qp.y,cb.y)), __fmul_rn(qp.z,cb.z));
            d1 = __fsub_rn(__fadd_rn(__fmul_rn(2.0f,dot), qn), cb.w);
        }
        {
            float dot = __fadd_rn(__fadd_rn(__fmul_rn(qp.x,cc.x), __fmul_rn(qp.y,cc.y)), __fmul_rn(qp.z,cc.z));
            d2 = __fsub_rn(__fadd_rn(__fmul_rn(2.0f,dot), qn), cc.w);
        }
        {
            float dot = __fadd_rn(__fadd_rn(__fmul_rn(qp.x,cd.x), __fmul_rn(qp.y,cd.y)), __fmul_rn(qp.z,cd.z));
            d3 = __fsub_rn(__fadd_rn(__fmul_rn(2.0f,dot), qn), cd.w);
        }
        insert10(dl, il, d0, c0 + t + 0);
        insert10(dl, il, d1, c0 + t + 1);
        insert10(dl, il, d2, c0 + t + 2);
        insert10(dl, il, d3, c0 + t + 3);
    }
    long o = ((long)(b*NN + q) * NCHUNK + chunk) * 10;
#pragma unroll
    for (int j = 0; j < 10; j++) { pd[o+j] = dl[j]; pi[o+j] = il[j]; }
}

// ---------------------------------------------------------------- merge + geometry + feat + h1 + BN1 stats
__global__ __launch_bounds__(256) void geom_k(const float4* __restrict__ pts,
                                              const float* __restrict__ pd, const int* __restrict__ pi,
                                              const float* __restrict__ w1,
                                              float* __restrict__ h1, float* __restrict__ stats) {
    __shared__ float sw1[49];
    if (threadIdx.x < 49) sw1[threadIdx.x] = w1[threadIdx.x];
    __syncthreads();

    int g = blockIdx.x * 256 + threadIdx.x;      // 0..32767
    int b = g >> 13, n = g & (NN-1);

    // merge sorted partial lists via sorted insert (scan order preserves tie rules)
    float dl[10]; int il[10];
#pragma unroll
    for (int j = 0; j < 10; j++) { dl[j] = -INFINITY; il[j] = 0; }
    const float* pdg = pd + (long)g * (NCHUNK*10);
    const int*   pig = pi + (long)g * (NCHUNK*10);
    for (int e = 0; e < NCHUNK*10; e++) {
        insert10(dl, il, pdg[e], pig[e]);
    }

    // gather 9 neighbors (skip slot 0 = self), relative vectors + phi
    float4 qp = pts[b*NN + n];
    float vx[9], vy[9], vz[9], ph[9];
#pragma unroll
    for (int t = 0; t < 9; t++) {
        float4 p4 = pts[b*NN + il[t+1]];
        vx[t] = p4.x - qp.x; vy[t] = p4.y - qp.y; vz[t] = p4.z - qp.z;
        ph[t] = atan2f(vy[t], vx[t]) / 6.283185307179586f + 0.5f;
    }

    // stable rank sort by phi (static indexing, branchless scatter)
    int rank[9];
#pragma unroll
    for (int t = 0; t < 9; t++) {
        int r = 0;
#pragma unroll
        for (int u = 0; u < 9; u++) {
            if (u == t) continue;
            bool before = (ph[u] < ph[t]) || (ph[u] == ph[t] && u < t);
            r += before ? 1 : 0;
        }
        rank[t] = r;
    }
    float sx[9], sy[9], sz[9];
#pragma unroll
    for (int s = 0; s < 9; s++) {
        float a = 0.f, bb = 0.f, c = 0.f;
#pragma unroll
        for (int t = 0; t < 9; t++) {
            bool m = (rank[t] == s);
            a = m ? vx[t] : a; bb = m ? vy[t] : bb; c = m ? vz[t] : c;
        }
        sx[s] = a; sy[s] = bb; sz[s] = c;
    }

    // sign from first (k=0) normal's x component
    float sgn;
    {
        float ax = sx[0], ay = sy[0], az = sz[0];
        float bx = sx[1], by = sy[1], bz = sz[1];
        float nx0 = ay*bz - az*by + 1e-5f;
        float ny0 = az*bx - ax*bz + 1e-5f;
        float nz0 = ax*by - ay*bx + 1e-5f;
        float inv = 1.0f / sqrtf(nx0*nx0 + ny0*ny0 + nz0*nz0);
        sgn = (nx0*inv > 0.0f) ? 1.0f : -1.0f;
    }

    float sum[7], sumsq[7];
#pragma unroll
    for (int o = 0; o < 7; o++) { sum[o] = 0.f; sumsq[o] = 0.f; }

#pragma unroll
    for (int t = 0; t < 9; t++) {
        const int t2 = (t + 1) % 9;
        float ax = sx[t],  ay = sy[t],  az = sz[t];
        float bx = sx[t2], by = sy[t2], bz = sz[t2];
        float cx = 0.5f*(ax+bx), cy = 0.5f*(ay+by), cz = 0.5f*(az+bz);
        float nx0 = ay*bz - az*by + 1e-5f;
        float ny0 = az*bx - ax*bz + 1e-5f;
        float nz0 = ax*by - ay*bx + 1e-5f;
        float inv = 1.0f / sqrtf(nx0*nx0 + ny0*ny0 + nz0*nz0);
        float nx = nx0*inv*sgn, ny = ny0*inv*sgn, nz = nz0*inv*sgn;
        float pos = (cx*nx + cy*ny + cz*nz) / 1.7320508075688772f;

        float f[7] = {cx, cy, cz, nx, ny, nz, pos};
        float* outp = h1 + ((long)g*9 + t) * 7;
#pragma unroll
        for (int o = 0; o < 7; o++) {
            float h = 0.f;
#pragma unroll
            for (int c = 0; c < 7; c++) h += f[c] * sw1[o*7 + c];
            outp[o] = h;
            sum[o] += h; sumsq[o] += h*h;
        }
    }

    // wave reduce + atomics for BN1 stats
#pragma unroll
    for (int o = 0; o < 7; o++) {
        float s  = sum[o];
        float s2 = sumsq[o];
        for (int off = 32; off > 0; off >>= 1) { s += __shfl_down(s, off); s2 += __shfl_down(s2, off); }
        if ((threadIdx.x & 63) == 0) {
            atomicAdd(&stats[o], s);
            atomicAdd(&stats[7 + o], s2);
        }
    }
}

// ---------------------------------------------------------------- bn1 + relu + w2 + bias2 -> h2, BN2 stats
__global__ __launch_bounds__(256) void mm2_k(const float* __restrict__ h1,
                                             const float* __restrict__ gamma1, const float* __restrict__ beta1,
                                             const float* __restrict__ w2, const float* __restrict__ bias2,
                                             float* __restrict__ h2, float* __restrict__ stats) {
    int g = blockIdx.x * 256 + threadIdx.x;      // 0..M_ELEMS-1 (grid exact)
    const float invM = 1.0f / (float)M_ELEMS;
    float s1[7], b1[7];
#pragma unroll
    for (int c = 0; c < 7; c++) {
        float m = stats[c] * invM;
        float v = stats[7 + c] * invM - m*m;
        float sc = gamma1[c] / sqrtf(v + BN_EPS);
        s1[c] = sc; b1[c] = beta1[c] - m*sc;
    }
    float a[7];
    const float* hh = h1 + (long)g * 7;
#pragma unroll
    for (int c = 0; c < 7; c++) a[c] = fmaxf(hh[c]*s1[c] + b1[c], 0.0f);

    float sum[7], sumsq[7];
#pragma unroll
    for (int o = 0; o < 7; o++) {
        float h = 0.f;
#pragma unroll
        for (int c = 0; c < 7; c++) h += a[c] * w2[o*7 + c];
        h += bias2[o];
        h2[(long)g*7 + o] = h;
        sum[o] = h; sumsq[o] = h*h;
    }

    // wave reduce -> shared across 4 waves -> 1 atomic set per block
    __shared__ float acc[14];
    if (threadIdx.x < 14) acc[threadIdx.x] = 0.f;
    __syncthreads();
#pragma unroll
    for (int o = 0; o < 7; o++) {
        float s  = sum[o];
        float s2 = sumsq[o];
        for (int off = 32; off > 0; off >>= 1) { s += __shfl_down(s, off); s2 += __shfl_down(s2, off); }
        if ((threadIdx.x & 63) == 0) {
            atomicAdd(&acc[o], s);
            atomicAdd(&acc[7 + o], s2);
        }
    }
    __syncthreads();
    if (threadIdx.x < 14) atomicAdd(&stats[14 + threadIdx.x], acc[threadIdx.x]);
}

// ---------------------------------------------------------------- bn2 + relu + w3 + bias3 + maxpool -> out
__global__ __launch_bounds__(256) void final_k(const float* __restrict__ x,
                                               const float* __restrict__ h2,
                                               const float* __restrict__ gamma2, const float* __restrict__ beta2,
                                               const float* __restrict__ w3, const float* __restrict__ bias3,
                                               const float* __restrict__ stats, float* __restrict__ out) {
    int g = blockIdx.x * 256 + threadIdx.x;      // 0..32767
    const float invM = 1.0f / (float)M_ELEMS;
    float s2v[7], b2v[7];
#pragma unroll
    for (int c = 0; c < 7; c++) {
        float m = stats[14 + c] * invM;
        float v = stats[21 + c] * invM - m*m;
        float sc = gamma2[c] / sqrtf(v + BN_EPS);
        s2v[c] = sc; b2v[c] = beta2[c] - m*sc;
    }
    float pooled[7];
#pragma unroll
    for (int o = 0; o < 7; o++) pooled[o] = -INFINITY;

    const float* hh = h2 + (long)g * 63;
#pragma unroll
    for (int t = 0; t < 9; t++) {
        float a[7];
#pragma unroll
        for (int c = 0; c < 7; c++) a[c] = fmaxf(hh[t*7 + c]*s2v[c] + b2v[c], 0.0f);
#pragma unroll
        for (int o = 0; o < 7; o++) {
            float h = 0.f;
#pragma unroll
            for (int c = 0; c < 7; c++) h += a[c] * w3[o*7 + c];
            h += bias3[o];
            pooled[o] = fmaxf(pooled[o], h);
        }
    }
    out[g*10 + 0] = x[g*3 + 0];
    out[g*10 + 1] = x[g*3 + 1];
    out[g*10 + 2] = x[g*3 + 2];
#pragma unroll
    for (int o = 0; o < 7; o++) out[g*10 + 3 + o] = pooled[o];
}

extern "C" void kernel_launch(void* const* d_in, const int* in_sizes, int n_in,
                              void* d_out, int out_size, void* d_ws, size_t ws_size,
                              hipStream_t stream) {
    const float* x      = (const float*)d_in[0];
    const float* w1     = (const float*)d_in[1];
    const float* gamma1 = (const float*)d_in[2];
    const float* beta1  = (const float*)d_in[3];
    const float* w2     = (const float*)d_in[4];
    const float* bias2  = (const float*)d_in[5];
    const float* gamma2 = (const float*)d_in[6];
    const float* beta2  = (const float*)d_in[7];
    const float* w3     = (const float*)d_in[8];
    const float* bias3  = (const float*)d_in[9];
    float* out = (float*)d_out;

    char* ws = (char*)d_ws;
    float4* pts  = (float4*)(ws + OFF_PTS);
    float*  pd   = (float*)(ws + OFF_PD);
    int*    pi   = (int*)(ws + OFF_PI);
    float*  h1   = (float*)(ws + OFF_H1);
    float*  h2   = (float*)(ws + OFF_H2);
    float*  stats= (float*)(ws + OFF_STATS);

    hipMemsetAsync(stats, 0, 28 * sizeof(float), stream);
    pack_k <<<TOTAL/256, 256, 0, stream>>>(x, pts);
    knn_k  <<<dim3(NN/256, NCHUNK, BB), 256, 0, stream>>>(pts, pd, pi);
    geom_k <<<TOTAL/256, 256, 0, stream>>>(pts, pd, pi, w1, h1, stats);
    mm2_k  <<<M_ELEMS/256, 256, 0, stream>>>(h1, gamma1, beta1, w2, bias2, h2, stats);
    final_k<<<TOTAL/256, 256, 0, stream>>>(x, h2, gamma2, beta2, w3, bias3, stats, out);
}

// Round 3
// 509.058 us; speedup vs baseline: 1.3244x; 1.3244x over previous
//
#include <hip/hip_runtime.h>
#include <math.h>

#define BB 4
#define NN 8192
#define TOTAL (BB*NN)        // 32768 points
#define KNBR 9
#define CH 7
#define NCHUNK 8
#define CHUNK (NN/NCHUNK)    // 1024
#define WARM 256             // always-insert region (P(trigger)~1)
#define BN_EPS 1e-5f
#define M_ELEMS (TOTAL*KNBR) // 294912

// workspace layout (bytes); lifetimes:
//   pts: pack->geom   pd/pi: knn->geom   h1: geom->mm2
//   h2: mm2->final (overlaps pts+pd head, dead by then)   stats: geom->final
#define OFF_PTS   0                        // 524288
#define OFF_PD    524288                   // 32768*80*4 = 10485760
#define OFF_PI    11010048                 // 10485760
#define OFF_STATS 21495808                 // 112 (pad to 512)
#define OFF_H1    21496320                 // 8257536, ends 29753856
#define OFF_H2    0                        // 8257536 (aliases dead pts/pd region)

// ---------------------------------------------------------------- pack x -> (x,y,z,|x|^2)
__global__ __launch_bounds__(256) void pack_k(const float* __restrict__ x, float4* __restrict__ pts) {
    int i = blockIdx.x * 256 + threadIdx.x;
    if (i >= TOTAL) return;
    float a = x[3*i], b = x[3*i+1], c = x[3*i+2];
    // match reference rounding: (a*a + b*b) + c*c, no fma contraction
    float sq = __fadd_rn(__fadd_rn(__fmul_rn(a,a), __fmul_rn(b,b)), __fmul_rn(c,c));
    pts[i] = make_float4(a, b, c, sq);
}

// unconditional sorted-shift insert body (desc by d; strict > => lower index
// wins ties in scan order, matching lax.top_k). No-op if d <= dl[9].
__device__ __forceinline__ void ibody(float (&dl)[10], int (&il)[10], float d, int ii) {
    bool c0 = d > dl[0];
#pragma unroll
    for (int p = 9; p > 0; p--) {
        bool here = d > dl[p];
        bool up   = d > dl[p-1];
        float nd = up ? dl[p-1] : d;
        int   ni = up ? il[p-1] : ii;
        if (here) { dl[p] = nd; il[p] = ni; }
    }
    if (c0) { dl[0] = d; il[0] = ii; }
}

__device__ __forceinline__ void insert10(float (&dl)[10], int (&il)[10], float d, int ii) {
    if (d > dl[9]) ibody(dl, il, d, ii);
}

__device__ __forceinline__ float distf(float4 qp, float qn, float4 cp) {
    float dot = __fadd_rn(__fadd_rn(__fmul_rn(qp.x,cp.x), __fmul_rn(qp.y,cp.y)), __fmul_rn(qp.z,cp.z));
    return __fsub_rn(__fadd_rn(__fmul_rn(2.0f,dot), qn), cp.w);  // 2*xx - xsq_n - xsq_m
}

// ---------------------------------------------------------------- KNN partial top-10 per candidate chunk
// Stores transposed: pd[(chunk*10+j)*TOTAL + g] so knn stores and geom loads coalesce.
__global__ __launch_bounds__(256) void knn_k(const float4* __restrict__ pts,
                                             float* __restrict__ pd, int* __restrict__ pi) {
    int b = blockIdx.z, chunk = blockIdx.y;
    int q = blockIdx.x * 256 + threadIdx.x;      // query index within batch
    const float4* __restrict__ base = pts + b * NN;
    float4 qp = base[q];
    float qn = -qp.w;                            // -xsq_n

    __shared__ float4 tile[CHUNK];
    const int c0 = chunk * CHUNK;
#pragma unroll
    for (int j = 0; j < CHUNK/256; j++)
        tile[threadIdx.x + j*256] = base[c0 + threadIdx.x + j*256];
    __syncthreads();

    float dl[10]; int il[10];
#pragma unroll
    for (int j = 0; j < 10; j++) { dl[j] = -INFINITY; il[j] = 0; }

    // warm region: trigger probability ~1 -> run body unconditionally (no branch)
    for (int j = 0; j < WARM; j++) {
        float d = distf(qp, qn, tile[j]);
        ibody(dl, il, d, c0 + j);
    }
    // tail: pairs under one combined branch (condition checked pre-insert is
    // safe: dl[9] only rises, so a skipped candidate could never qualify)
    for (int j = WARM; j < CHUNK; j += 2) {
        float4 ca = tile[j], cb = tile[j+1];
        float d0 = distf(qp, qn, ca);
        float d1 = distf(qp, qn, cb);
        if (d0 > dl[9] || d1 > dl[9]) {
            ibody(dl, il, d0, c0 + j);
            ibody(dl, il, d1, c0 + j + 1);
        }
    }

    int g = b*NN + q;
#pragma unroll
    for (int j = 0; j < 10; j++) {
        int e = chunk*10 + j;
        pd[(long)e*TOTAL + g] = dl[j];
        pi[(long)e*TOTAL + g] = il[j];
    }
}

// ---------------------------------------------------------------- merge + geometry + feat + h1 + BN1 stats
__global__ __launch_bounds__(256) void geom_k(const float4* __restrict__ pts,
                                              const float* __restrict__ pd, const int* __restrict__ pi,
                                              const float* __restrict__ w1,
                                              float* __restrict__ h1, float* __restrict__ stats) {
    __shared__ float sw1[49];
    __shared__ float acc[14];
    if (threadIdx.x < 49) sw1[threadIdx.x] = w1[threadIdx.x];
    if (threadIdx.x < 14) acc[threadIdx.x] = 0.f;
    __syncthreads();

    int g = blockIdx.x * 256 + threadIdx.x;      // 0..32767
    int b = g >> 13, n = g & (NN-1);

    // merge sorted partial lists (ascending chunk order + desc-within-list
    // preserves lax.top_k tie rules)
    float dl[10]; int il[10];
#pragma unroll
    for (int j = 0; j < 10; j++) { dl[j] = -INFINITY; il[j] = 0; }
    for (int e = 0; e < NCHUNK*10; e++) {
        insert10(dl, il, pd[(long)e*TOTAL + g], pi[(long)e*TOTAL + g]);
    }

    // gather 9 neighbors (skip slot 0 = self), relative vectors + phi
    float4 qp = pts[b*NN + n];
    float vx[9], vy[9], vz[9], ph[9];
#pragma unroll
    for (int t = 0; t < 9; t++) {
        float4 p4 = pts[b*NN + il[t+1]];
        vx[t] = p4.x - qp.x; vy[t] = p4.y - qp.y; vz[t] = p4.z - qp.z;
        ph[t] = atan2f(vy[t], vx[t]) / 6.283185307179586f + 0.5f;
    }

    // stable rank sort by phi (static indexing, branchless scatter)
    int rank[9];
#pragma unroll
    for (int t = 0; t < 9; t++) {
        int r = 0;
#pragma unroll
        for (int u = 0; u < 9; u++) {
            if (u == t) continue;
            bool before = (ph[u] < ph[t]) || (ph[u] == ph[t] && u < t);
            r += before ? 1 : 0;
        }
        rank[t] = r;
    }
    float sx[9], sy[9], sz[9];
#pragma unroll
    for (int s = 0; s < 9; s++) {
        float a = 0.f, bb = 0.f, c = 0.f;
#pragma unroll
        for (int t = 0; t < 9; t++) {
            bool m = (rank[t] == s);
            a = m ? vx[t] : a; bb = m ? vy[t] : bb; c = m ? vz[t] : c;
        }
        sx[s] = a; sy[s] = bb; sz[s] = c;
    }

    // sign from first (k=0) normal's x component
    float sgn;
    {
        float ax = sx[0], ay = sy[0], az = sz[0];
        float bx = sx[1], by = sy[1], bz = sz[1];
        float nx0 = ay*bz - az*by + 1e-5f;
        float ny0 = az*bx - ax*bz + 1e-5f;
        float nz0 = ax*by - ay*bx + 1e-5f;
        float inv = 1.0f / sqrtf(nx0*nx0 + ny0*ny0 + nz0*nz0);
        sgn = (nx0*inv > 0.0f) ? 1.0f : -1.0f;
    }

    float sum[7], sumsq[7];
#pragma unroll
    for (int o = 0; o < 7; o++) { sum[o] = 0.f; sumsq[o] = 0.f; }

#pragma unroll
    for (int t = 0; t < 9; t++) {
        const int t2 = (t + 1) % 9;
        float ax = sx[t],  ay = sy[t],  az = sz[t];
        float bx = sx[t2], by = sy[t2], bz = sz[t2];
        float cx = 0.5f*(ax+bx), cy = 0.5f*(ay+by), cz = 0.5f*(az+bz);
        float nx0 = ay*bz - az*by + 1e-5f;
        float ny0 = az*bx - ax*bz + 1e-5f;
        float nz0 = ax*by - ay*bx + 1e-5f;
        float inv = 1.0f / sqrtf(nx0*nx0 + ny0*ny0 + nz0*nz0);
        float nx = nx0*inv*sgn, ny = ny0*inv*sgn, nz = nz0*inv*sgn;
        float pos = (cx*nx + cy*ny + cz*nz) / 1.7320508075688772f;

        float f[7] = {cx, cy, cz, nx, ny, nz, pos};
        float* outp = h1 + ((long)g*9 + t) * 7;
#pragma unroll
        for (int o = 0; o < 7; o++) {
            float h = 0.f;
#pragma unroll
            for (int c = 0; c < 7; c++) h += f[c] * sw1[o*7 + c];
            outp[o] = h;
            sum[o] += h; sumsq[o] += h*h;
        }
    }

    // wave reduce -> block LDS -> one atomic set per block
#pragma unroll
    for (int o = 0; o < 7; o++) {
        float s  = sum[o];
        float s2 = sumsq[o];
        for (int off = 32; off > 0; off >>= 1) { s += __shfl_down(s, off); s2 += __shfl_down(s2, off); }
        if ((threadIdx.x & 63) == 0) {
            atomicAdd(&acc[o], s);
            atomicAdd(&acc[7 + o], s2);
        }
    }
    __syncthreads();
    if (threadIdx.x < 14) atomicAdd(&stats[threadIdx.x], acc[threadIdx.x]);
}

// ---------------------------------------------------------------- bn1 + relu + w2 + bias2 -> h2, BN2 stats
__global__ __launch_bounds__(256) void mm2_k(const float* __restrict__ h1,
                                             const float* __restrict__ gamma1, const float* __restrict__ beta1,
                                             const float* __restrict__ w2, const float* __restrict__ bias2,
                                             float* __restrict__ h2, float* __restrict__ stats) {
    int g = blockIdx.x * 256 + threadIdx.x;      // 0..M_ELEMS-1 (grid exact)
    const float invM = 1.0f / (float)M_ELEMS;
    float s1[7], b1[7];
#pragma unroll
    for (int c = 0; c < 7; c++) {
        float m = stats[c] * invM;
        float v = stats[7 + c] * invM - m*m;
        float sc = gamma1[c] / sqrtf(v + BN_EPS);
        s1[c] = sc; b1[c] = beta1[c] - m*sc;
    }
    float a[7];
    const float* hh = h1 + (long)g * 7;
#pragma unroll
    for (int c = 0; c < 7; c++) a[c] = fmaxf(hh[c]*s1[c] + b1[c], 0.0f);

    float sum[7], sumsq[7];
#pragma unroll
    for (int o = 0; o < 7; o++) {
        float h = 0.f;
#pragma unroll
        for (int c = 0; c < 7; c++) h += a[c] * w2[o*7 + c];
        h += bias2[o];
        h2[(long)g*7 + o] = h;
        sum[o] = h; sumsq[o] = h*h;
    }

    __shared__ float acc[14];
    if (threadIdx.x < 14) acc[threadIdx.x] = 0.f;
    __syncthreads();
#pragma unroll
    for (int o = 0; o < 7; o++) {
        float s  = sum[o];
        float s2 = sumsq[o];
        for (int off = 32; off > 0; off >>= 1) { s += __shfl_down(s, off); s2 += __shfl_down(s2, off); }
        if ((threadIdx.x & 63) == 0) {
            atomicAdd(&acc[o], s);
            atomicAdd(&acc[7 + o], s2);
        }
    }
    __syncthreads();
    if (threadIdx.x < 14) atomicAdd(&stats[14 + threadIdx.x], acc[threadIdx.x]);
}

// ---------------------------------------------------------------- bn2 + relu + w3 + bias3 + maxpool -> out
__global__ __launch_bounds__(256) void final_k(const float* __restrict__ x,
                                               const float* __restrict__ h2,
                                               const float* __restrict__ gamma2, const float* __restrict__ beta2,
                                               const float* __restrict__ w3, const float* __restrict__ bias3,
                                               const float* __restrict__ stats, float* __restrict__ out) {
    int g = blockIdx.x * 256 + threadIdx.x;      // 0..32767
    const float invM = 1.0f / (float)M_ELEMS;
    float s2v[7], b2v[7];
#pragma unroll
    for (int c = 0; c < 7; c++) {
        float m = stats[14 + c] * invM;
        float v = stats[21 + c] * invM - m*m;
        float sc = gamma2[c] / sqrtf(v + BN_EPS);
        s2v[c] = sc; b2v[c] = beta2[c] - m*sc;
    }
    float pooled[7];
#pragma unroll
    for (int o = 0; o < 7; o++) pooled[o] = -INFINITY;

    const float* hh = h2 + (long)g * 63;
#pragma unroll
    for (int t = 0; t < 9; t++) {
        float a[7];
#pragma unroll
        for (int c = 0; c < 7; c++) a[c] = fmaxf(hh[t*7 + c]*s2v[c] + b2v[c], 0.0f);
#pragma unroll
        for (int o = 0; o < 7; o++) {
            float h = 0.f;
#pragma unroll
            for (int c = 0; c < 7; c++) h += a[c] * w3[o*7 + c];
            h += bias3[o];
            pooled[o] = fmaxf(pooled[o], h);
        }
    }
    out[g*10 + 0] = x[g*3 + 0];
    out[g*10 + 1] = x[g*3 + 1];
    out[g*10 + 2] = x[g*3 + 2];
#pragma unroll
    for (int o = 0; o < 7; o++) out[g*10 + 3 + o] = pooled[o];
}

extern "C" void kernel_launch(void* const* d_in, const int* in_sizes, int n_in,
                              void* d_out, int out_size, void* d_ws, size_t ws_size,
                              hipStream_t stream) {
    const float* x      = (const float*)d_in[0];
    const float* w1     = (const float*)d_in[1];
    const float* gamma1 = (const float*)d_in[2];
    const float* beta1  = (const float*)d_in[3];
    const float* w2     = (const float*)d_in[4];
    const float* bias2  = (const float*)d_in[5];
    const float* gamma2 = (const float*)d_in[6];
    const float* beta2  = (const float*)d_in[7];
    const float* w3     = (const float*)d_in[8];
    const float* bias3  = (const float*)d_in[9];
    float* out = (float*)d_out;

    char* ws = (char*)d_ws;
    float4* pts  = (float4*)(ws + OFF_PTS);
    float*  pd   = (float*)(ws + OFF_PD);
    int*    pi   = (int*)(ws + OFF_PI);
    float*  h1   = (float*)(ws + OFF_H1);
    float*  h2   = (float*)(ws + OFF_H2);
    float*  stats= (float*)(ws + OFF_STATS);

    hipMemsetAsync(stats, 0, 28 * sizeof(float), stream);
    pack_k <<<TOTAL/256, 256, 0, stream>>>(x, pts);
    knn_k  <<<dim3(NN/256, NCHUNK, BB), 256, 0, stream>>>(pts, pd, pi);
    geom_k <<<TOTAL/256, 256, 0, stream>>>(pts, pd, pi, w1, h1, stats);
    mm2_k  <<<M_ELEMS/256, 256, 0, stream>>>(h1, gamma1, beta1, w2, bias2, h2, stats);
    final_k<<<TOTAL/256, 256, 0, stream>>>(x, h2, gamma2, beta2, w3, bias3, stats, out);
}